// Round 7
// baseline (189.827 us; speedup 1.0000x reference)
//
#include <hip/hip_runtime.h>
#include <cstdint>

#define LX 16384
#define NB 16
#define LT 64
#define TPB 4                 // l-tiles per block; grid.x = LX/(LT*TPB) = 64 -> 1024 blocks = 4/CU, one round
#define HALO 8
#define XI (LT + 2*HALO)      // 80 staged positions
#define XPD 36                // x row pitch in dwords (144 B, 16B-aligned; chunk-rotated)

typedef __attribute__((ext_vector_type(2))) _Float16 h2;
typedef __attribute__((ext_vector_type(8))) _Float16 h8;
typedef __attribute__((ext_vector_type(4))) unsigned u4;
typedef __attribute__((ext_vector_type(4))) float f4;

static __device__ __forceinline__ h2 u2h(unsigned u) {
    union { unsigned u; h2 h; } v; v.u = u; return v.h;
}
static __device__ __forceinline__ unsigned h2u(h2 h) {
    union { h2 h; unsigned u; } v; v.h = h; return v.u;
}
static __device__ __forceinline__ unsigned pkrtz(float a, float b) {
    auto r = __builtin_amdgcn_cvt_pkrtz(a, b);        // __fp16 ext_vector(2)
    union { decltype(r) h; unsigned u; } v; v.h = r;
    return v.u;
}

// raw barriers: __syncthreads() drains vmcnt(0) and would kill the x prefetch.
#define BAR_LGKM() do { asm volatile("s_waitcnt lgkmcnt(0)" ::: "memory"); \
                        __builtin_amdgcn_s_barrier();                      \
                        asm volatile("" ::: "memory"); } while (0)
#define BAR_RAW()  do { asm volatile("" ::: "memory");                     \
                        __builtin_amdgcn_s_barrier();                      \
                        asm volatile("" ::: "memory"); } while (0)

// ---------------- kernel 0: prep weights into ws (all f16) ----------------
// ws: A2 f16[64][192] @0 (24576 B)  A2[o*192 + tap*64 + c] = weight[o][c][tap]
//   | beff f32[6] @24576
//   | wcg u32[14*256] @24608 (14336 B): combined offset/mask conv weights,
//     pre-fragmented for mfma_f32_16x16x32_f16 A-operand.
//     step s, thread t (lane=t>>2, d=t&3): m=lane&15, q=lane>>4, j=s>>1,
//     c=(s&1)*32+q*8+2d : packs (W[m][c][j], W[m][c+1][j]),
//     W[m][c][j] = pw[m][c]*dw[c][j] (m<3: off branch, 3..5: msk, else 0)
__global__ void prep_kernel(const float* __restrict__ weight,
                            const float* __restrict__ b_off_pw, const float* __restrict__ w_off_pw,
                            const float* __restrict__ b_off_dw,
                            const float* __restrict__ b_msk_pw, const float* __restrict__ w_msk_pw,
                            const float* __restrict__ b_msk_dw,
                            const float* __restrict__ w_off_dw, const float* __restrict__ w_msk_dw,
                            short* __restrict__ A2, float* __restrict__ beff,
                            unsigned* __restrict__ wcg) {
    int bid = blockIdx.x;
    int t = threadIdx.x;
    if (bid < 48) {
        int idx = bid * 256 + t;                  // 0..12287 : A2[o][tap*64+c]
        int o = idx / 192;
        int rem = idx - o * 192;
        int tap = rem >> 6, c = rem & 63;
        union { _Float16 h; short s; } v;
        v.h = (_Float16)weight[o * 192 + c * 3 + tap];
        A2[idx] = v.s;
    } else {
        // combined offset/mask conv weights, A-fragment order
        int lane = t >> 2, d = t & 3;
        int m = lane & 15, qq = lane >> 4;
        #pragma unroll
        for (int s = 0; s < 14; ++s) {
            int j = s >> 1;
            int c = (s & 1) * 32 + qq * 8 + 2 * d;
            float w0 = 0.f, w1 = 0.f;
            if (m < 3) {
                w0 = w_off_pw[m * 64 + c]     * w_off_dw[c * 7 + j];
                w1 = w_off_pw[m * 64 + c + 1] * w_off_dw[(c + 1) * 7 + j];
            } else if (m < 6) {
                w0 = w_msk_pw[(m - 3) * 64 + c]     * w_msk_dw[c * 7 + j];
                w1 = w_msk_pw[(m - 3) * 64 + c + 1] * w_msk_dw[(c + 1) * 7 + j];
            }
            wcg[s * 256 + t] = pkrtz(w0, w1);
        }
        if (t < 6) {
            int br = t / 3, m3 = t % 3;
            const float* pw = br ? w_msk_pw : w_off_pw;
            const float* bd = br ? b_msk_dw : b_off_dw;
            const float* bp = br ? b_msk_pw : b_off_pw;
            float s = bp[m3];
            for (int c = 0; c < 64; ++c) s += pw[m3 * 64 + c] * bd[c];
            beff[t] = s;
        }
    }
}

// ---------------- main fused kernel ----------------
// Occupancy lever (round-7): round 6 compiled to only 80 VGPRs, so the
// (256,3)/170-reg concession is unnecessary -- the spills in rounds 2-5 came
// from the launder live-range games, not from wfr residency itself. Go back
// to __launch_bounds__(256,4) (128-reg cap, 48 regs slack) and SINGLE-buffer
// xdw so LDS = 36384 B -> 4 blocks/CU (16 waves vs 12). The cost is one
// BAR_RAW before each inter-tile write_x (3x per block, measured cheap in
// round 5). TPB=4 -> grid 1024 = exactly one residency round (no tail),
// A2/wfr prologue amortized over 4 tiles. Tile loop unroll 1 (one ~7 KB
// body, round-5 I-cache lesson). wfr[14] (56 regs) loaded once per block,
// register-resident. Phase-2 outputs stay wave-local (regs + shfl): no
// phase2->phase3 barrier.
__launch_bounds__(256, 4)
__global__ void deform_main(const float* __restrict__ x,
                            const float* __restrict__ bias,
                            const short* __restrict__ A2,
                            const float* __restrict__ beff,
                            const unsigned* __restrict__ wcg,
                            float* __restrict__ out) {
    // x tile f16 [i][c], c-pairs as dwords; 8-dword chunks rotated by row: phys = (chunk + i) & 3
    __shared__ __align__(16) unsigned xdw[XI * XPD];        // 11520 B
    // A2 staged in LDS, XOR-swizzled: phys_dw = row*96 + (dw ^ ((row&7)<<2))
    __shared__ __align__(16) unsigned A2l[6144];            // 24576 B
    __shared__ float bias_l[64];                            // 256 B
    __shared__ float beff_l[8];                             // 32 B
    // total 36384 B -> 4 blocks/CU

    const int t = threadIdx.x;
    const int lane = t & 63;
    const int wv = t >> 6;
    const int r = lane & 15, q = lane >> 4;
    const int lbase = blockIdx.x * (LT * TPB);
    const int b = blockIdx.y;
    const float* xb = x + (size_t)b * (64 * LX);

    // register staging for the next x tile (issue in phase 3 / write at tile end)
    f4 rx0[3], rx1[3];

    auto issue_x = [&](int l0v) {
        #pragma unroll
        for (int s = 0; s < 3; ++s) {
            int p = t + 256 * s;
            rx0[s] = (f4){0.f, 0.f, 0.f, 0.f};
            rx1[s] = (f4){0.f, 0.f, 0.f, 0.f};
            if (p < 640) {
                int cp = p & 31, up = p >> 5;
                int g4 = l0v - HALO + up * 4;
                if ((unsigned)g4 < (unsigned)LX) {
                    rx0[s] = *(const f4*)(xb + (size_t)(2 * cp) * LX + g4);
                    rx1[s] = *(const f4*)(xb + (size_t)(2 * cp + 1) * LX + g4);
                }
            }
        }
    };
    auto write_x = [&]() {
        #pragma unroll
        for (int s = 0; s < 3; ++s) {
            int p = t + 256 * s;
            if (p < 640) {
                int cp = p & 31, up = p >> 5;
                #pragma unroll
                for (int d = 0; d < 4; ++d) {
                    int i = up * 4 + d;
                    int pc = ((cp >> 3) + i) & 3;
                    xdw[i * XPD + pc * 8 + (cp & 7)] = pkrtz(rx0[s][d], rx1[s][d]);
                }
            }
        }
    };

    // ---- prologue: issue x tile 0, stage A2, load weight fragments (kept
    //      in registers for the whole kernel), write tile 0 ----
    issue_x(lbase);
    {
        const u4* A2g4 = (const u4*)A2;          // 1536 u4, coalesced 16B/lane
        #pragma unroll
        for (int s = 0; s < 6; ++s) {
            int idx = t + 256 * s;               // 0..1535
            int row = idx / 24;
            int g = idx - row * 24;
            int pdw = row * 96 + ((g * 4) ^ ((row & 7) << 2));
            *(u4*)&A2l[pdw] = A2g4[idx];
        }
    }
    u4 wfr[14];
    {
        const u4* wc4 = (const u4*)wcg;
        #pragma unroll
        for (int s = 0; s < 14; ++s) wfr[s] = wc4[s * 64 + lane];
    }
    if (t < 64) bias_l[t] = bias[t];
    if (t < 6)  beff_l[t] = beff[t];
    write_x();                                   // waits vmcnt for tile-0 loads
    BAR_LGKM();

    #pragma unroll 1
    for (int tt = 0; tt < TPB; ++tt) {
        const int l0 = lbase + tt * LT;

        // ---- phase 2: offset/mask conv as MFMA, M=16(6 used) K=448 N=16/wave ----
        // D row m (0..2 off, 3..5 msk), col l = wv*16 + (lane&15).
        // Two accumulator chains (7 deep each) halve the serial MFMA latency.
        unsigned mywp = 0; int myli = 0;
        {
            f4 acc2a = {0.f, 0.f, 0.f, 0.f};
            f4 acc2b = {0.f, 0.f, 0.f, 0.f};
            const int irow = wv * 16 + r + 5;            // + j
            #pragma unroll
            for (int s = 0; s < 14; ++s) {
                const int j = s >> 1, half = s & 1;
                const int i = irow + j;
                const int chunk = half * 2 + (q >> 1);
                const int pd = i * XPD + (((chunk + i) & 3) << 3) + ((q & 1) << 2);
                union { u4 u; h8 h; } bx; bx.u = *(const u4*)&xdw[pd];
                union { u4 u; h8 h; } ax; ax.u = wfr[s];
                if (s & 1)
                    acc2b = __builtin_amdgcn_mfma_f32_16x16x32_f16(ax.h, bx.h, acc2b, 0, 0, 0);
                else
                    acc2a = __builtin_amdgcn_mfma_f32_16x16x32_f16(ax.h, bx.h, acc2a, 0, 0, 0);
            }
            f4 acc2 = acc2a + acc2b;
            // epilogue: gather (off_k, msk_k) per lane q=k (k=0..2), col r
            float b0 = __shfl(acc2[0], r);           // off0: q0.e0
            float b1 = __shfl(acc2[1], r);           // off1: q0.e1
            float b2 = __shfl(acc2[2], r);           // off2: q0.e2
            float m0 = __shfl(acc2[3], r);           // msk0: q0.e3
            float m1 = __shfl(acc2[0], 16 + r);      // msk1: q1.e0
            float m2 = __shfl(acc2[1], 16 + r);      // msk2: q1.e1
            if (q < 3) {
                const int k = q, l = wv * 16 + r;
                float off = (k == 0 ? b0 : k == 1 ? b1 : b2) + beff_l[k];
                float z   = (k == 0 ? m0 : k == 1 ? m1 : m2) + beff_l[3 + k];
                float msk = 1.0f / (1.0f + __expf(-z));
                float p = (float)(l0 + l - 1 + k) + off;   // ref op order
                float fl = floorf(p);
                int i0 = (int)fl, i1 = i0 + 1;
                float fr = p - fl;
                int li0 = i0 - l0 + HALO, li1 = li0 + 1;
                float w0 = (((unsigned)i0 < (unsigned)LX) && ((unsigned)li0 < (unsigned)XI)) ? (1.0f - fr) * msk : 0.0f;
                float w1 = (((unsigned)i1 < (unsigned)LX) && ((unsigned)li1 < (unsigned)XI)) ? fr * msk : 0.0f;
                li0 = min(max(li0, 0), XI - 2);            // rows li0, li0+1 both staged
                mywp = pkrtz(w0, w1);
                myli = li0;
            }
        }
        // no barrier: kl data is wave-local (shfl), xdw/A2l are read-only here

        // ---- phase 3 start: issue next x tile's global loads (HBM latency
        //      hides under phase 3's MFMA + stores) ----
        if (tt + 1 < TPB) issue_x(l0 + LT);

        // ---- phase 3: out[o][l] = W2[o][(tap,c)] @ xs[(tap,c)][l], M=64 K=192 N=64 ----
        {
            const int lcol = wv * 16 + r;
            unsigned wpt[3]; int lit[3];
            #pragma unroll
            for (int tap = 0; tap < 3; ++tap) {
                wpt[tap] = __shfl(mywp, tap * 16 + r);
                lit[tap] = __shfl(myli, tap * 16 + r);
            }
            f4 acc[4];
            #pragma unroll
            for (int mt = 0; mt < 4; ++mt) acc[mt] = (f4){0.f, 0.f, 0.f, 0.f};
            const int sw = (r & 7) << 2;
            #pragma unroll
            for (int kk = 0; kk < 6; ++kk) {
                const int tap = kk >> 1;
                unsigned wp = wpt[tap];
                unsigned w00 = __builtin_amdgcn_perm(wp, wp, 0x01000100u);  // (w0,w0)
                unsigned w11 = __builtin_amdgcn_perm(wp, wp, 0x03020302u);  // (w1,w1)
                int li0 = lit[tap];
                int cp0 = ((kk & 1) << 4) + (q << 2);      // dword idx {0,4,...,28}
                int chunkL = cp0 >> 3;
                int o0 = li0 * XPD + ((((chunkL + li0) & 3) << 3) | (cp0 & 7));
                int o1 = (li0 + 1) * XPD + ((((chunkL + li0 + 1) & 3) << 3) | (cp0 & 7));
                u4 r0 = *(const u4*)&xdw[o0];
                u4 r1 = *(const u4*)&xdw[o1];
                u4 xs;
                #pragma unroll
                for (int d = 0; d < 4; ++d)
                    xs[d] = h2u(u2h(r0[d]) * u2h(w00) + u2h(r1[d]) * u2h(w11));
                union { u4 u; h8 h; } bfr; bfr.u = xs;
                #pragma unroll
                for (int mt = 0; mt < 4; ++mt) {
                    union { u4 u; h8 h; } af;
                    af.u = *(const u4*)&A2l[(mt * 16 + r) * 96 + ((kk * 16 + q * 4) ^ sw)];
                    acc[mt] = __builtin_amdgcn_mfma_f32_16x16x32_f16(af.h, bfr.h, acc[mt], 0, 0, 0);
                }
            }
            #pragma unroll
            for (int mt = 0; mt < 4; ++mt) {
                int ob = mt * 16 + 4 * q;     // D row o = mt*16 + 4q + e, col l = lcol
                float* op = out + ((size_t)b * 64 + ob) * LX + l0 + lcol;
                #pragma unroll
                for (int e = 0; e < 4; ++e)
                    op[(size_t)e * LX] = acc[mt][e] + bias_l[ob + e];
            }
        }

        // ---- inter-tile: publish prefetched x tile t+1 ----
        if (tt < TPB - 1) {
            BAR_RAW();                         // all xdw readers of tile tt done
            write_x();                         // waits vmcnt only for rx regs
            BAR_LGKM();                        // new xdw visible for next phase 2
        }
    }
}

extern "C" void kernel_launch(void* const* d_in, const int* in_sizes, int n_in,
                              void* d_out, int out_size, void* d_ws, size_t ws_size,
                              hipStream_t stream) {
    const float* x        = (const float*)d_in[0];
    const float* w_off_dw = (const float*)d_in[1];
    const float* b_off_dw = (const float*)d_in[2];
    const float* w_off_pw = (const float*)d_in[3];
    const float* b_off_pw = (const float*)d_in[4];
    const float* w_msk_dw = (const float*)d_in[5];
    const float* b_msk_dw = (const float*)d_in[6];
    const float* w_msk_pw = (const float*)d_in[7];
    const float* b_msk_pw = (const float*)d_in[8];
    const float* weight   = (const float*)d_in[9];
    const float* bias     = (const float*)d_in[10];
    float* out = (float*)d_out;

    short*    A2   = (short*)d_ws;                     // 24576 B
    float*    beff = (float*)((char*)d_ws + 24576);    // 24 B (padded to 32)
    unsigned* wcg  = (unsigned*)((char*)d_ws + 24608); // 14336 B

    hipLaunchKernelGGL(prep_kernel, dim3(49), dim3(256), 0, stream,
                       weight, b_off_pw, w_off_pw, b_off_dw, b_msk_pw, w_msk_pw, b_msk_dw,
                       w_off_dw, w_msk_dw, A2, beff, wcg);
    hipLaunchKernelGGL(deform_main, dim3(LX / (LT * TPB), NB), dim3(256), 0, stream,
                       x, bias, A2, beff, wcg, out);
}

// Round 8
// 159.229 us; speedup vs baseline: 1.1922x; 1.1922x over previous
//
#include <hip/hip_runtime.h>
#include <cstdint>

#define LX 16384
#define NB 16
#define LT 64
#define TPB 2                 // l-tiles per block; grid.x = 128 -> 2048 blocks = 2 full rounds at 4/CU
#define HALO 8
#define XI (LT + 2*HALO)      // 80 staged positions
#define XPD 36                // x row pitch in dwords (144 B, 16B-aligned; chunk-rotated)

typedef __attribute__((ext_vector_type(2))) _Float16 h2;
typedef __attribute__((ext_vector_type(8))) _Float16 h8;
typedef __attribute__((ext_vector_type(4))) unsigned u4;
typedef __attribute__((ext_vector_type(4))) float f4;

static __device__ __forceinline__ h2 u2h(unsigned u) {
    union { unsigned u; h2 h; } v; v.u = u; return v.h;
}
static __device__ __forceinline__ unsigned h2u(h2 h) {
    union { h2 h; unsigned u; } v; v.h = h; return v.u;
}
static __device__ __forceinline__ unsigned pkrtz(float a, float b) {
    auto r = __builtin_amdgcn_cvt_pkrtz(a, b);        // __fp16 ext_vector(2)
    union { decltype(r) h; unsigned u; } v; v.h = r;
    return v.u;
}

// raw barriers: __syncthreads() drains vmcnt(0) and would kill the x prefetch.
#define BAR_LGKM() do { asm volatile("s_waitcnt lgkmcnt(0)" ::: "memory"); \
                        __builtin_amdgcn_s_barrier();                      \
                        asm volatile("" ::: "memory"); } while (0)
#define BAR_RAW()  do { asm volatile("" ::: "memory");                     \
                        __builtin_amdgcn_s_barrier();                      \
                        asm volatile("" ::: "memory"); } while (0)

// ---------------- kernel 0: prep weights into ws (all f16) ----------------
// ws: A2 f16[64][192] @0 (24576 B)  A2[o*192 + tap*64 + c] = weight[o][c][tap]
//   | beff f32[6] @24576
//   | wcg u32[14*256] @24608 (14336 B): combined offset/mask conv weights,
//     pre-fragmented for mfma_f32_16x16x32_f16 A-operand.
//     step s, thread t (lane=t>>2, d=t&3): m=lane&15, q=lane>>4, j=s>>1,
//     c=(s&1)*32+q*8+2d : packs (W[m][c][j], W[m][c+1][j]),
//     W[m][c][j] = pw[m][c]*dw[c][j] (m<3: off branch, 3..5: msk, else 0)
__global__ void prep_kernel(const float* __restrict__ weight,
                            const float* __restrict__ b_off_pw, const float* __restrict__ w_off_pw,
                            const float* __restrict__ b_off_dw,
                            const float* __restrict__ b_msk_pw, const float* __restrict__ w_msk_pw,
                            const float* __restrict__ b_msk_dw,
                            const float* __restrict__ w_off_dw, const float* __restrict__ w_msk_dw,
                            short* __restrict__ A2, float* __restrict__ beff,
                            unsigned* __restrict__ wcg) {
    int bid = blockIdx.x;
    int t = threadIdx.x;
    if (bid < 48) {
        int idx = bid * 256 + t;                  // 0..12287 : A2[o][tap*64+c]
        int o = idx / 192;
        int rem = idx - o * 192;
        int tap = rem >> 6, c = rem & 63;
        union { _Float16 h; short s; } v;
        v.h = (_Float16)weight[o * 192 + c * 3 + tap];
        A2[idx] = v.s;
    } else {
        // combined offset/mask conv weights, A-fragment order
        int lane = t >> 2, d = t & 3;
        int m = lane & 15, qq = lane >> 4;
        #pragma unroll
        for (int s = 0; s < 14; ++s) {
            int j = s >> 1;
            int c = (s & 1) * 32 + qq * 8 + 2 * d;
            float w0 = 0.f, w1 = 0.f;
            if (m < 3) {
                w0 = w_off_pw[m * 64 + c]     * w_off_dw[c * 7 + j];
                w1 = w_off_pw[m * 64 + c + 1] * w_off_dw[(c + 1) * 7 + j];
            } else if (m < 6) {
                w0 = w_msk_pw[(m - 3) * 64 + c]     * w_msk_dw[c * 7 + j];
                w1 = w_msk_pw[(m - 3) * 64 + c + 1] * w_msk_dw[(c + 1) * 7 + j];
            }
            wcg[s * 256 + t] = pkrtz(w0, w1);
        }
        if (t < 6) {
            int br = t / 3, m3 = t % 3;
            const float* pw = br ? w_msk_pw : w_off_pw;
            const float* bd = br ? b_msk_dw : b_off_dw;
            const float* bp = br ? b_msk_pw : b_off_pw;
            float s = bp[m3];
            for (int c = 0; c < 64; ++c) s += pw[m3 * 64 + c] * bd[c];
            beff[t] = s;
        }
    }
}

// ---------------- main fused kernel ----------------
// Round-8 occupancy fix. Empirical rule from R3-R7: wfr-resident under a
// 128-reg compile budget (launch_bounds(256,4)) ALWAYS spills to scratch
// (R7: +87/+41 MB on FETCH/WRITE, 80 us); under the 170-reg budget
// (launch_bounds(256,3)) it compiles clean at VGPR=80 (+~24 AGPR). But the
// second launch_bounds arg is only the COMPILER budget -- runtime residency
// is min(LDS cap, actual-register cap). R6's 3-block limit was the 47.9 KB
// double-buffered LDS, not registers (80+24 <= 128 allows 4 waves/SIMD).
// So: keep (256,3) (no spill), SINGLE-buffer xdw -> LDS 36384 B ->
// 4 x 36384 = 145.5 KB <= 160 KB -> hardware schedules 4 blocks/CU =
// 16 waves. Cost: one BAR_RAW before the inter-tile write_x (once per
// block at TPB=2; measured cheap in R5). TPB=2 -> 2048 blocks = exactly
// 2 residency rounds at 4/CU (and still 89% packing if only 3 fit).
// wfr[14] (56 regs) register-resident for the whole kernel; phase-2
// outputs wave-local (regs + shfl): no phase2->phase3 barrier.
__launch_bounds__(256, 3)
__global__ void deform_main(const float* __restrict__ x,
                            const float* __restrict__ bias,
                            const short* __restrict__ A2,
                            const float* __restrict__ beff,
                            const unsigned* __restrict__ wcg,
                            float* __restrict__ out) {
    // x tile f16 [i][c], c-pairs as dwords; 8-dword chunks rotated by row: phys = (chunk + i) & 3
    __shared__ __align__(16) unsigned xdw[XI * XPD];        // 11520 B
    // A2 staged in LDS, XOR-swizzled: phys_dw = row*96 + (dw ^ ((row&7)<<2))
    __shared__ __align__(16) unsigned A2l[6144];            // 24576 B
    __shared__ float bias_l[64];                            // 256 B
    __shared__ float beff_l[8];                             // 32 B
    // total 36384 B -> 4 blocks/CU (LDS-wise)

    const int t = threadIdx.x;
    const int lane = t & 63;
    const int wv = t >> 6;
    const int r = lane & 15, q = lane >> 4;
    const int lbase = blockIdx.x * (LT * TPB);
    const int b = blockIdx.y;
    const float* xb = x + (size_t)b * (64 * LX);

    // register staging for the next x tile (issue in phase 3 / write at tile end)
    f4 rx0[3], rx1[3];

    auto issue_x = [&](int l0v) {
        #pragma unroll
        for (int s = 0; s < 3; ++s) {
            int p = t + 256 * s;
            rx0[s] = (f4){0.f, 0.f, 0.f, 0.f};
            rx1[s] = (f4){0.f, 0.f, 0.f, 0.f};
            if (p < 640) {
                int cp = p & 31, up = p >> 5;
                int g4 = l0v - HALO + up * 4;
                if ((unsigned)g4 < (unsigned)LX) {
                    rx0[s] = *(const f4*)(xb + (size_t)(2 * cp) * LX + g4);
                    rx1[s] = *(const f4*)(xb + (size_t)(2 * cp + 1) * LX + g4);
                }
            }
        }
    };
    auto write_x = [&]() {
        #pragma unroll
        for (int s = 0; s < 3; ++s) {
            int p = t + 256 * s;
            if (p < 640) {
                int cp = p & 31, up = p >> 5;
                #pragma unroll
                for (int d = 0; d < 4; ++d) {
                    int i = up * 4 + d;
                    int pc = ((cp >> 3) + i) & 3;
                    xdw[i * XPD + pc * 8 + (cp & 7)] = pkrtz(rx0[s][d], rx1[s][d]);
                }
            }
        }
    };

    // ---- prologue: issue x tile 0, stage A2, load weight fragments (kept
    //      in registers for the whole kernel), write tile 0 ----
    issue_x(lbase);
    {
        const u4* A2g4 = (const u4*)A2;          // 1536 u4, coalesced 16B/lane
        #pragma unroll
        for (int s = 0; s < 6; ++s) {
            int idx = t + 256 * s;               // 0..1535
            int row = idx / 24;
            int g = idx - row * 24;
            int pdw = row * 96 + ((g * 4) ^ ((row & 7) << 2));
            *(u4*)&A2l[pdw] = A2g4[idx];
        }
    }
    u4 wfr[14];
    {
        const u4* wc4 = (const u4*)wcg;
        #pragma unroll
        for (int s = 0; s < 14; ++s) wfr[s] = wc4[s * 64 + lane];
    }
    if (t < 64) bias_l[t] = bias[t];
    if (t < 6)  beff_l[t] = beff[t];
    write_x();                                   // waits vmcnt for tile-0 loads
    BAR_LGKM();

    #pragma unroll 1
    for (int tt = 0; tt < TPB; ++tt) {
        const int l0 = lbase + tt * LT;

        // ---- phase 2: offset/mask conv as MFMA, M=16(6 used) K=448 N=16/wave ----
        // D row m (0..2 off, 3..5 msk), col l = wv*16 + (lane&15).
        // Two accumulator chains (7 deep each) halve the serial MFMA latency.
        unsigned mywp = 0; int myli = 0;
        {
            f4 acc2a = {0.f, 0.f, 0.f, 0.f};
            f4 acc2b = {0.f, 0.f, 0.f, 0.f};
            const int irow = wv * 16 + r + 5;            // + j
            #pragma unroll
            for (int s = 0; s < 14; ++s) {
                const int j = s >> 1, half = s & 1;
                const int i = irow + j;
                const int chunk = half * 2 + (q >> 1);
                const int pd = i * XPD + (((chunk + i) & 3) << 3) + ((q & 1) << 2);
                union { u4 u; h8 h; } bx; bx.u = *(const u4*)&xdw[pd];
                union { u4 u; h8 h; } ax; ax.u = wfr[s];
                if (s & 1)
                    acc2b = __builtin_amdgcn_mfma_f32_16x16x32_f16(ax.h, bx.h, acc2b, 0, 0, 0);
                else
                    acc2a = __builtin_amdgcn_mfma_f32_16x16x32_f16(ax.h, bx.h, acc2a, 0, 0, 0);
            }
            f4 acc2 = acc2a + acc2b;
            // epilogue: gather (off_k, msk_k) per lane q=k (k=0..2), col r
            float b0 = __shfl(acc2[0], r);           // off0: q0.e0
            float b1 = __shfl(acc2[1], r);           // off1: q0.e1
            float b2 = __shfl(acc2[2], r);           // off2: q0.e2
            float m0 = __shfl(acc2[3], r);           // msk0: q0.e3
            float m1 = __shfl(acc2[0], 16 + r);      // msk1: q1.e0
            float m2 = __shfl(acc2[1], 16 + r);      // msk2: q1.e1
            if (q < 3) {
                const int k = q, l = wv * 16 + r;
                float off = (k == 0 ? b0 : k == 1 ? b1 : b2) + beff_l[k];
                float z   = (k == 0 ? m0 : k == 1 ? m1 : m2) + beff_l[3 + k];
                float msk = 1.0f / (1.0f + __expf(-z));
                float p = (float)(l0 + l - 1 + k) + off;   // ref op order
                float fl = floorf(p);
                int i0 = (int)fl, i1 = i0 + 1;
                float fr = p - fl;
                int li0 = i0 - l0 + HALO, li1 = li0 + 1;
                float w0 = (((unsigned)i0 < (unsigned)LX) && ((unsigned)li0 < (unsigned)XI)) ? (1.0f - fr) * msk : 0.0f;
                float w1 = (((unsigned)i1 < (unsigned)LX) && ((unsigned)li1 < (unsigned)XI)) ? fr * msk : 0.0f;
                li0 = min(max(li0, 0), XI - 2);            // rows li0, li0+1 both staged
                mywp = pkrtz(w0, w1);
                myli = li0;
            }
        }
        // no barrier: kl data is wave-local (shfl), xdw/A2l are read-only here

        // ---- phase 3 start: issue next x tile's global loads (HBM latency
        //      hides under phase 3's MFMA + stores) ----
        if (tt + 1 < TPB) issue_x(l0 + LT);

        // ---- phase 3: out[o][l] = W2[o][(tap,c)] @ xs[(tap,c)][l], M=64 K=192 N=64 ----
        {
            const int lcol = wv * 16 + r;
            unsigned wpt[3]; int lit[3];
            #pragma unroll
            for (int tap = 0; tap < 3; ++tap) {
                wpt[tap] = __shfl(mywp, tap * 16 + r);
                lit[tap] = __shfl(myli, tap * 16 + r);
            }
            f4 acc[4];
            #pragma unroll
            for (int mt = 0; mt < 4; ++mt) acc[mt] = (f4){0.f, 0.f, 0.f, 0.f};
            const int sw = (r & 7) << 2;
            #pragma unroll
            for (int kk = 0; kk < 6; ++kk) {
                const int tap = kk >> 1;
                unsigned wp = wpt[tap];
                unsigned w00 = __builtin_amdgcn_perm(wp, wp, 0x01000100u);  // (w0,w0)
                unsigned w11 = __builtin_amdgcn_perm(wp, wp, 0x03020302u);  // (w1,w1)
                int li0 = lit[tap];
                int cp0 = ((kk & 1) << 4) + (q << 2);      // dword idx {0,4,...,28}
                int chunkL = cp0 >> 3;
                int o0 = li0 * XPD + ((((chunkL + li0) & 3) << 3) | (cp0 & 7));
                int o1 = (li0 + 1) * XPD + ((((chunkL + li0 + 1) & 3) << 3) | (cp0 & 7));
                u4 r0 = *(const u4*)&xdw[o0];
                u4 r1 = *(const u4*)&xdw[o1];
                u4 xs;
                #pragma unroll
                for (int d = 0; d < 4; ++d)
                    xs[d] = h2u(u2h(r0[d]) * u2h(w00) + u2h(r1[d]) * u2h(w11));
                union { u4 u; h8 h; } bfr; bfr.u = xs;
                #pragma unroll
                for (int mt = 0; mt < 4; ++mt) {
                    union { u4 u; h8 h; } af;
                    af.u = *(const u4*)&A2l[(mt * 16 + r) * 96 + ((kk * 16 + q * 4) ^ sw)];
                    acc[mt] = __builtin_amdgcn_mfma_f32_16x16x32_f16(af.h, bfr.h, acc[mt], 0, 0, 0);
                }
            }
            #pragma unroll
            for (int mt = 0; mt < 4; ++mt) {
                int ob = mt * 16 + 4 * q;     // D row o = mt*16 + 4q + e, col l = lcol
                float* op = out + ((size_t)b * 64 + ob) * LX + l0 + lcol;
                #pragma unroll
                for (int e = 0; e < 4; ++e)
                    op[(size_t)e * LX] = acc[mt][e] + bias_l[ob + e];
            }
        }

        // ---- inter-tile: publish prefetched x tile t+1 (single buffer:
        //      must wait for all readers of tile tt first) ----
        if (tt < TPB - 1) {
            BAR_RAW();                         // all xdw readers of tile tt done
            write_x();                         // waits vmcnt only for rx regs
            BAR_LGKM();                        // new xdw visible for next phase 2
        }
    }
}

extern "C" void kernel_launch(void* const* d_in, const int* in_sizes, int n_in,
                              void* d_out, int out_size, void* d_ws, size_t ws_size,
                              hipStream_t stream) {
    const float* x        = (const float*)d_in[0];
    const float* w_off_dw = (const float*)d_in[1];
    const float* b_off_dw = (const float*)d_in[2];
    const float* w_off_pw = (const float*)d_in[3];
    const float* b_off_pw = (const float*)d_in[4];
    const float* w_msk_dw = (const float*)d_in[5];
    const float* b_msk_dw = (const float*)d_in[6];
    const float* w_msk_pw = (const float*)d_in[7];
    const float* b_msk_pw = (const float*)d_in[8];
    const float* weight   = (const float*)d_in[9];
    const float* bias     = (const float*)d_in[10];
    float* out = (float*)d_out;

    short*    A2   = (short*)d_ws;                     // 24576 B
    float*    beff = (float*)((char*)d_ws + 24576);    // 24 B (padded to 32)
    unsigned* wcg  = (unsigned*)((char*)d_ws + 24608); // 14336 B

    hipLaunchKernelGGL(prep_kernel, dim3(49), dim3(256), 0, stream,
                       weight, b_off_pw, w_off_pw, b_off_dw, b_msk_pw, w_msk_pw, b_msk_dw,
                       w_off_dw, w_msk_dw, A2, beff, wcg);
    hipLaunchKernelGGL(deform_main, dim3(LX / (LT * TPB), NB), dim3(256), 0, stream,
                       x, bias, A2, beff, wcg, out);
}

// Round 9
// 152.256 us; speedup vs baseline: 1.2468x; 1.0458x over previous
//
#include <hip/hip_runtime.h>
#include <cstdint>

#define LX 16384
#define NB 16
#define LT 64
#define TPB 2                 // l-tiles per block; grid.x = 128 -> 2048 blocks = 2 rounds at 4/CU
#define HALO 8
#define XI (LT + 2*HALO)      // 80 staged positions
#define XPD 36                // x row pitch in dwords (144 B, 16B-aligned; chunk-rotated)

typedef __attribute__((ext_vector_type(2))) _Float16 h2;
typedef __attribute__((ext_vector_type(8))) _Float16 h8;
typedef __attribute__((ext_vector_type(4))) unsigned u4;
typedef __attribute__((ext_vector_type(4))) float f4;

static __device__ __forceinline__ h2 u2h(unsigned u) {
    union { unsigned u; h2 h; } v; v.u = u; return v.h;
}
static __device__ __forceinline__ unsigned h2u(h2 h) {
    union { h2 h; unsigned u; } v; v.h = h; return v.u;
}
static __device__ __forceinline__ unsigned pkrtz(float a, float b) {
    auto r = __builtin_amdgcn_cvt_pkrtz(a, b);        // __fp16 ext_vector(2)
    union { decltype(r) h; unsigned u; } v; v.h = r;
    return v.u;
}

// raw barriers: __syncthreads() drains vmcnt(0) and would kill the x prefetch.
#define BAR_LGKM() do { asm volatile("s_waitcnt lgkmcnt(0)" ::: "memory"); \
                        __builtin_amdgcn_s_barrier();                      \
                        asm volatile("" ::: "memory"); } while (0)
#define BAR_RAW()  do { asm volatile("" ::: "memory");                     \
                        __builtin_amdgcn_s_barrier();                      \
                        asm volatile("" ::: "memory"); } while (0)

// ---------------- kernel 0: prep weights into ws (all f16) ----------------
// ws: A2 f16[64][192] @0 (24576 B), stored PRE-SWIZZLED in the exact physical
//     LDS order deform_main uses (phys u4 index = o*24 + (g ^ (o&7)), g =
//     logical u4 within row) so the main kernel can stage it with linear
//     global_load_lds_dwordx4 (wave-uniform LDS dest + lane*16).
//   | beff f32[6] @24576
//   | wcg u32[14*256] @24608 (14336 B): combined offset/mask conv weights,
//     pre-fragmented for mfma_f32_16x16x32_f16 A-operand.
//     step s, thread t (lane=t>>2, d=t&3): m=lane&15, q=lane>>4, j=s>>1,
//     c=(s&1)*32+q*8+2d : packs (W[m][c][j], W[m][c+1][j]),
//     W[m][c][j] = pw[m][c]*dw[c][j] (m<3: off branch, 3..5: msk, else 0)
__global__ void prep_kernel(const float* __restrict__ weight,
                            const float* __restrict__ b_off_pw, const float* __restrict__ w_off_pw,
                            const float* __restrict__ b_off_dw,
                            const float* __restrict__ b_msk_pw, const float* __restrict__ w_msk_pw,
                            const float* __restrict__ b_msk_dw,
                            const float* __restrict__ w_off_dw, const float* __restrict__ w_msk_dw,
                            short* __restrict__ A2, float* __restrict__ beff,
                            unsigned* __restrict__ wcg) {
    int bid = blockIdx.x;
    int t = threadIdx.x;
    if (bid < 48) {
        int idx = bid * 256 + t;                  // logical 0..12287 : A2[o][tap*64+c]
        int o = idx / 192;
        int rem = idx - o * 192;
        int tap = rem >> 6, c = rem & 63;
        union { _Float16 h; short s; } v;
        v.h = (_Float16)weight[o * 192 + c * 3 + tap];
        // XOR-swizzled destination (matches deform_main's A2l read addressing):
        int g = rem >> 3, e = rem & 7;
        A2[o * 192 + ((g ^ (o & 7)) << 3) + e] = v.s;
    } else {
        // combined offset/mask conv weights, A-fragment order
        int lane = t >> 2, d = t & 3;
        int m = lane & 15, qq = lane >> 4;
        #pragma unroll
        for (int s = 0; s < 14; ++s) {
            int j = s >> 1;
            int c = (s & 1) * 32 + qq * 8 + 2 * d;
            float w0 = 0.f, w1 = 0.f;
            if (m < 3) {
                w0 = w_off_pw[m * 64 + c]     * w_off_dw[c * 7 + j];
                w1 = w_off_pw[m * 64 + c + 1] * w_off_dw[(c + 1) * 7 + j];
            } else if (m < 6) {
                w0 = w_msk_pw[(m - 3) * 64 + c]     * w_msk_dw[c * 7 + j];
                w1 = w_msk_pw[(m - 3) * 64 + c + 1] * w_msk_dw[(c + 1) * 7 + j];
            }
            wcg[s * 256 + t] = pkrtz(w0, w1);
        }
        if (t < 6) {
            int br = t / 3, m3 = t % 3;
            const float* pw = br ? w_msk_pw : w_off_pw;
            const float* bd = br ? b_msk_dw : b_off_dw;
            const float* bp = br ? b_msk_pw : b_off_pw;
            float s = bp[m3];
            for (int c = 0; c < 64; ++c) s += pw[m3 * 64 + c] * bd[c];
            beff[t] = s;
        }
    }
}

// ---------------- main fused kernel ----------------
// Round-9: R8's LDS goal (single-buffer xdw, 36384 B -> 4 blocks/CU fit) on
// R6's proven compile shape. Cross-round evidence: wfr-resident + RUNTIME
// tile loop (unroll 1) spills to scratch regardless of budget (R7: +87 MB,
// R8: +16 MB WRITE); wfr-resident + FULL unroll at (256,3) compiles clean
// at 80 VGPR (+~24 AGPR = ~104 <= 128/wave, R6). So: full #pragma unroll of
// the TPB=2 loop (2x body ~14 KB, fits L1I; R5's I-cache issue was the 4x
// body), (256,3) budget, single xdw buffer + BAR_RAW before the one
// inter-tile write_x. With total regs <= 128 and LDS*4 = 145.5 <= 160 KB
// the HW schedules 4 blocks/CU = 16 waves (R6 had 12). A2 is staged via 6
// global_load_lds_dwordx4 per wave from the pre-swizzled ws copy (no VGPR
// round-trip / ds_writes); explicit vmcnt(0) before the prologue barrier
// guarantees it landed. Phase-2 outputs wave-local (regs + shfl): no
// phase2->phase3 barrier.
__launch_bounds__(256, 3)
__global__ void deform_main(const float* __restrict__ x,
                            const float* __restrict__ bias,
                            const short* __restrict__ A2,
                            const float* __restrict__ beff,
                            const unsigned* __restrict__ wcg,
                            float* __restrict__ out) {
    // x tile f16 [i][c], c-pairs as dwords; 8-dword chunks rotated by row: phys = (chunk + i) & 3
    __shared__ __align__(16) unsigned xdw[XI * XPD];        // 11520 B
    // A2 staged in LDS, XOR-swizzled: phys_dw = row*96 + (dw ^ ((row&7)<<2))
    __shared__ __align__(16) unsigned A2l[6144];            // 24576 B
    __shared__ float bias_l[64];                            // 256 B
    __shared__ float beff_l[8];                             // 32 B
    // total 36384 B -> 4 blocks/CU (LDS-wise)

    const int t = threadIdx.x;
    const int lane = t & 63;
    const int wv = t >> 6;
    const int r = lane & 15, q = lane >> 4;
    const int lbase = blockIdx.x * (LT * TPB);
    const int b = blockIdx.y;
    const float* xb = x + (size_t)b * (64 * LX);

    // register staging for the next x tile (issue in phase 3 / write at tile end)
    f4 rx0[3], rx1[3];

    auto issue_x = [&](int l0v) {
        #pragma unroll
        for (int s = 0; s < 3; ++s) {
            int p = t + 256 * s;
            rx0[s] = (f4){0.f, 0.f, 0.f, 0.f};
            rx1[s] = (f4){0.f, 0.f, 0.f, 0.f};
            if (p < 640) {
                int cp = p & 31, up = p >> 5;
                int g4 = l0v - HALO + up * 4;
                if ((unsigned)g4 < (unsigned)LX) {
                    rx0[s] = *(const f4*)(xb + (size_t)(2 * cp) * LX + g4);
                    rx1[s] = *(const f4*)(xb + (size_t)(2 * cp + 1) * LX + g4);
                }
            }
        }
    };
    auto write_x = [&]() {
        #pragma unroll
        for (int s = 0; s < 3; ++s) {
            int p = t + 256 * s;
            if (p < 640) {
                int cp = p & 31, up = p >> 5;
                #pragma unroll
                for (int d = 0; d < 4; ++d) {
                    int i = up * 4 + d;
                    int pc = ((cp >> 3) + i) & 3;
                    xdw[i * XPD + pc * 8 + (cp & 7)] = pkrtz(rx0[s][d], rx1[s][d]);
                }
            }
        }
    };

    // ---- prologue: stage A2 direct-to-LDS (async), issue x tile 0, load
    //      weight fragments (register-resident for the whole kernel),
    //      write tile 0, drain, barrier ----
    {
        const u4* A2g4 = (const u4*)A2;          // pre-swizzled: linear copy
        #pragma unroll
        for (int s = 0; s < 6; ++s) {
            int ib = (s * 4 + wv) * 64;          // u4 index base (wave-uniform)
            __builtin_amdgcn_global_load_lds(
                (const __attribute__((address_space(1))) void*)(A2g4 + ib + lane),
                (__attribute__((address_space(3))) void*)(&A2l[ib * 4]),
                16, 0, 0);
        }
    }
    issue_x(lbase);
    u4 wfr[14];
    {
        const u4* wc4 = (const u4*)wcg;
        #pragma unroll
        for (int s = 0; s < 14; ++s) wfr[s] = wc4[s * 64 + lane];
    }
    if (t < 64) bias_l[t] = bias[t];
    if (t < 6)  beff_l[t] = beff[t];
    write_x();                                   // waits vmcnt for tile-0 loads
    asm volatile("s_waitcnt vmcnt(0)" ::: "memory");   // A2 global_load_lds landed
    BAR_LGKM();

    #pragma unroll
    for (int tt = 0; tt < TPB; ++tt) {
        const int l0 = lbase + tt * LT;

        // ---- phase 2: offset/mask conv as MFMA, M=16(6 used) K=448 N=16/wave ----
        // D row m (0..2 off, 3..5 msk), col l = wv*16 + (lane&15).
        // Two accumulator chains (7 deep each) halve the serial MFMA latency.
        unsigned mywp = 0; int myli = 0;
        {
            f4 acc2a = {0.f, 0.f, 0.f, 0.f};
            f4 acc2b = {0.f, 0.f, 0.f, 0.f};
            const int irow = wv * 16 + r + 5;            // + j
            #pragma unroll
            for (int s = 0; s < 14; ++s) {
                const int j = s >> 1, half = s & 1;
                const int i = irow + j;
                const int chunk = half * 2 + (q >> 1);
                const int pd = i * XPD + (((chunk + i) & 3) << 3) + ((q & 1) << 2);
                union { u4 u; h8 h; } bx; bx.u = *(const u4*)&xdw[pd];
                union { u4 u; h8 h; } ax; ax.u = wfr[s];
                if (s & 1)
                    acc2b = __builtin_amdgcn_mfma_f32_16x16x32_f16(ax.h, bx.h, acc2b, 0, 0, 0);
                else
                    acc2a = __builtin_amdgcn_mfma_f32_16x16x32_f16(ax.h, bx.h, acc2a, 0, 0, 0);
            }
            f4 acc2 = acc2a + acc2b;
            // epilogue: gather (off_k, msk_k) per lane q=k (k=0..2), col r
            float b0 = __shfl(acc2[0], r);           // off0: q0.e0
            float b1 = __shfl(acc2[1], r);           // off1: q0.e1
            float b2 = __shfl(acc2[2], r);           // off2: q0.e2
            float m0 = __shfl(acc2[3], r);           // msk0: q0.e3
            float m1 = __shfl(acc2[0], 16 + r);      // msk1: q1.e0
            float m2 = __shfl(acc2[1], 16 + r);      // msk2: q1.e1
            if (q < 3) {
                const int k = q, l = wv * 16 + r;
                float off = (k == 0 ? b0 : k == 1 ? b1 : b2) + beff_l[k];
                float z   = (k == 0 ? m0 : k == 1 ? m1 : m2) + beff_l[3 + k];
                float msk = 1.0f / (1.0f + __expf(-z));
                float p = (float)(l0 + l - 1 + k) + off;   // ref op order
                float fl = floorf(p);
                int i0 = (int)fl, i1 = i0 + 1;
                float fr = p - fl;
                int li0 = i0 - l0 + HALO, li1 = li0 + 1;
                float w0 = (((unsigned)i0 < (unsigned)LX) && ((unsigned)li0 < (unsigned)XI)) ? (1.0f - fr) * msk : 0.0f;
                float w1 = (((unsigned)i1 < (unsigned)LX) && ((unsigned)li1 < (unsigned)XI)) ? fr * msk : 0.0f;
                li0 = min(max(li0, 0), XI - 2);            // rows li0, li0+1 both staged
                mywp = pkrtz(w0, w1);
                myli = li0;
            }
        }
        // no barrier: kl data is wave-local (shfl), xdw/A2l are read-only here

        // ---- phase 3 start: issue next x tile's global loads (HBM latency
        //      hides under phase 3's MFMA + stores) ----
        if (tt + 1 < TPB) issue_x(l0 + LT);

        // ---- phase 3: out[o][l] = W2[o][(tap,c)] @ xs[(tap,c)][l], M=64 K=192 N=64 ----
        {
            const int lcol = wv * 16 + r;
            unsigned wpt[3]; int lit[3];
            #pragma unroll
            for (int tap = 0; tap < 3; ++tap) {
                wpt[tap] = __shfl(mywp, tap * 16 + r);
                lit[tap] = __shfl(myli, tap * 16 + r);
            }
            f4 acc[4];
            #pragma unroll
            for (int mt = 0; mt < 4; ++mt) acc[mt] = (f4){0.f, 0.f, 0.f, 0.f};
            const int sw = (r & 7) << 2;
            #pragma unroll
            for (int kk = 0; kk < 6; ++kk) {
                const int tap = kk >> 1;
                unsigned wp = wpt[tap];
                unsigned w00 = __builtin_amdgcn_perm(wp, wp, 0x01000100u);  // (w0,w0)
                unsigned w11 = __builtin_amdgcn_perm(wp, wp, 0x03020302u);  // (w1,w1)
                int li0 = lit[tap];
                int cp0 = ((kk & 1) << 4) + (q << 2);      // dword idx {0,4,...,28}
                int chunkL = cp0 >> 3;
                int o0 = li0 * XPD + ((((chunkL + li0) & 3) << 3) | (cp0 & 7));
                int o1 = (li0 + 1) * XPD + ((((chunkL + li0 + 1) & 3) << 3) | (cp0 & 7));
                u4 r0 = *(const u4*)&xdw[o0];
                u4 r1 = *(const u4*)&xdw[o1];
                u4 xs;
                #pragma unroll
                for (int d = 0; d < 4; ++d)
                    xs[d] = h2u(u2h(r0[d]) * u2h(w00) + u2h(r1[d]) * u2h(w11));
                union { u4 u; h8 h; } bfr; bfr.u = xs;
                #pragma unroll
                for (int mt = 0; mt < 4; ++mt) {
                    union { u4 u; h8 h; } af;
                    af.u = *(const u4*)&A2l[(mt * 16 + r) * 96 + ((kk * 16 + q * 4) ^ sw)];
                    acc[mt] = __builtin_amdgcn_mfma_f32_16x16x32_f16(af.h, bfr.h, acc[mt], 0, 0, 0);
                }
            }
            #pragma unroll
            for (int mt = 0; mt < 4; ++mt) {
                int ob = mt * 16 + 4 * q;     // D row o = mt*16 + 4q + e, col l = lcol
                float* op = out + ((size_t)b * 64 + ob) * LX + l0 + lcol;
                #pragma unroll
                for (int e = 0; e < 4; ++e)
                    op[(size_t)e * LX] = acc[mt][e] + bias_l[ob + e];
            }
        }

        // ---- inter-tile: publish prefetched x tile t+1 (single buffer:
        //      wait for all readers of tile tt first) ----
        if (tt < TPB - 1) {
            BAR_RAW();                         // all xdw readers of tile tt done
            write_x();                         // waits vmcnt only for rx regs
            BAR_LGKM();                        // new xdw visible for next phase 2
        }
    }
}

extern "C" void kernel_launch(void* const* d_in, const int* in_sizes, int n_in,
                              void* d_out, int out_size, void* d_ws, size_t ws_size,
                              hipStream_t stream) {
    const float* x        = (const float*)d_in[0];
    const float* w_off_dw = (const float*)d_in[1];
    const float* b_off_dw = (const float*)d_in[2];
    const float* w_off_pw = (const float*)d_in[3];
    const float* b_off_pw = (const float*)d_in[4];
    const float* w_msk_dw = (const float*)d_in[5];
    const float* b_msk_dw = (const float*)d_in[6];
    const float* w_msk_pw = (const float*)d_in[7];
    const float* b_msk_pw = (const float*)d_in[8];
    const float* weight   = (const float*)d_in[9];
    const float* bias     = (const float*)d_in[10];
    float* out = (float*)d_out;

    short*    A2   = (short*)d_ws;                     // 24576 B (pre-swizzled)
    float*    beff = (float*)((char*)d_ws + 24576);    // 24 B (padded to 32)
    unsigned* wcg  = (unsigned*)((char*)d_ws + 24608); // 14336 B

    hipLaunchKernelGGL(prep_kernel, dim3(49), dim3(256), 0, stream,
                       weight, b_off_pw, w_off_pw, b_off_dw, b_msk_pw, w_msk_pw, b_msk_dw,
                       w_off_dw, w_msk_dw, A2, beff, wcg);
    hipLaunchKernelGGL(deform_main, dim3(LX / (LT * TPB), NB), dim3(256), 0, stream,
                       x, bias, A2, beff, wcg, out);
}